// Round 8
// baseline (140.558 us; speedup 1.0000x reference)
//
#include <hip/hip_runtime.h>
#include <cstdint>
#include <cstddef>

#define CIN   256
#define COUT  256
#define CMID  64
#define H     64
#define W     64
#define HO    128
#define WO    128
#define BATCH 4

typedef unsigned short u16;
typedef unsigned int   u32;
typedef __attribute__((ext_vector_type(8))) __bf16 bf16x8;
typedef __attribute__((ext_vector_type(4))) float f32x4;

// Packed layouts (granule = 8 bf16 = 16 B, lane-contiguous):
//   Xt [b][y(65)][s=kc*4+q (32)][x(65)][8ci]   row = 16640 u16
//   X2t[b][y(65)][s=kc2*4+q (8)][x(65)][8cm]   row = 4160 u16
//   WPH[t(9)][kc(8)][q(4)][co(256)][8ci]
//   WPL[t(9)][kc2(2)][q(4)][co(256)][8cm]
// y==64 zero guard row; x==64 zero guard granule.
#define XT_ROW  16640
#define X2_ROW  4160

#define AS1 __attribute__((address_space(1)))
#define AS3 __attribute__((address_space(3)))

// global->LDS direct 16B copy; LDS dst is wave-uniform base, HW adds lane*16.
__device__ __forceinline__ void g2l16(const void* g, const void* l) {
    __builtin_amdgcn_global_load_lds((const AS1 u32*)(uintptr_t)g,
                                     (AS3 u32*)(u32)(uintptr_t)l, 16, 0, 0);
}

__device__ __forceinline__ u16 f2bf(float f) {
    u32 u = __builtin_bit_cast(u32, f);
    u += 0x7fffu + ((u >> 16) & 1u);          // RNE
    return (u16)(u >> 16);
}

// ---------------------------------------------------------------------------
// Fused prep (grid 332 = 260 input blocks + 72 weight-pack blocks). Unchanged.
// ---------------------------------------------------------------------------
__global__ __launch_bounds__(256) void k_prep(const float* __restrict__ inx,
                                              const float* __restrict__ w1,
                                              const float* __restrict__ b1,
                                              const float* __restrict__ wH,
                                              const float* __restrict__ wL,
                                              u16* __restrict__ Xt,
                                              u16* __restrict__ X2t,
                                              u16* __restrict__ WPH,
                                              u16* __restrict__ WPL) {
    __shared__ u16 sX[32 * 64 * 8];               // 32 KiB [s][x][8ci]
    __shared__ u16 sW1[8 * 4 * 64 * 8];           // 32 KiB [kc][q][cm][8ci]
    const int blk = blockIdx.x;
    const int tid = threadIdx.x;

    if (blk >= BATCH * 65) {                      // ---- weight-pack blocks ----
        const int pb = blk - BATCH * 65;
        const int t = pb / 8;
        const int kc = pb % 8;
        const int co = tid;
        #pragma unroll
        for (int q = 0; q < 4; ++q) {
            u16 pk[8];
            #pragma unroll
            for (int j = 0; j < 8; ++j) {
                int ci = kc * 32 + q * 8 + j;
                pk[j] = f2bf(wH[((size_t)ci * COUT + co) * 9 + t]);
            }
            *(uint4*)(WPH + ((((size_t)t * 8 + kc) * 4 + q) * 256 + co) * 8) = *(uint4*)pk;
        }
        if (kc < 2) {
            #pragma unroll
            for (int q = 0; q < 4; ++q) {
                u16 pk[8];
                #pragma unroll
                for (int j = 0; j < 8; ++j) {
                    int cm = kc * 32 + q * 8 + j;
                    pk[j] = f2bf(wL[((size_t)cm * COUT + co) * 9 + t]);
                }
                *(uint4*)(WPL + ((((size_t)t * 2 + kc) * 4 + q) * 256 + co) * 8) = *(uint4*)pk;
            }
        }
        return;
    }

    // ---- input blocks ----
    const int b = blk / 65;
    const int y = blk % 65;
    u16* xrow  = Xt  + (size_t)(b * 65 + y) * XT_ROW;
    u16* x2row = X2t + (size_t)(b * 65 + y) * X2_ROW;
    if (y == H) {                                 // zero guard rows
        uint4 z = {0, 0, 0, 0};
        for (int i = tid; i < XT_ROW / 8; i += 256) *(uint4*)(xrow + i * 8) = z;
        for (int i = tid; i < X2_ROW / 8; i += 256) *(uint4*)(x2row + i * 8) = z;
        return;
    }

    // W1 -> LDS
    #pragma unroll
    for (int i = 0; i < 16; ++i) {                // 4096 float4 / 256 threads
        int lin4 = i * 256 + tid;
        float4 v = ((const float4*)w1)[lin4];
        int lin = lin4 * 4;
        int cm = lin >> 8, ci = lin & 255;
        u16* dp = sW1 + (((size_t)(ci >> 3) * 64 + cm) * 8) + (ci & 7);
        dp[0] = f2bf(v.x); dp[1] = f2bf(v.y); dp[2] = f2bf(v.z); dp[3] = f2bf(v.w);
    }

    const int x = tid & 63, g0 = tid >> 6;
    #pragma unroll
    for (int gg = 0; gg < 8; ++gg) {
        const int s = gg * 4 + g0;                // s = kc*4+q, ci0 = s*8
        u16 pk[8];
        #pragma unroll
        for (int j = 0; j < 8; ++j)
            pk[j] = f2bf(inx[(((size_t)b * CIN + s * 8 + j) * H + y) * W + x]);
        uint4 v = *(uint4*)pk;
        *(uint4*)(xrow + ((size_t)s * 65 + x) * 8) = v;
        *(uint4*)(sX   + ((size_t)s * 64 + x) * 8) = v;
    }
    if (tid < 32) {                               // Xt x-guard granule
        uint4 z = {0, 0, 0, 0};
        *(uint4*)(xrow + ((size_t)tid * 65 + 64) * 8) = z;
    }
    if (tid < 8) {                                // X2t x-guard granule
        uint4 z = {0, 0, 0, 0};
        *(uint4*)(x2row + ((size_t)tid * 65 + 64) * 8) = z;
    }
    __syncthreads();

    // 1x1 bottleneck: M=64 cm x N=64 x, K=256.
    const int wv = tid >> 6, lane = tid & 63, l15 = lane & 15, q = lane >> 4;
    f32x4 acc[4] = {};
    #pragma unroll
    for (int kc = 0; kc < 8; ++kc) {
        bf16x8 bfr = *(const bf16x8*)(sX + ((size_t)(kc * 4 + q) * 64 + wv * 16 + l15) * 8);
        #pragma unroll
        for (int mi = 0; mi < 4; ++mi) {
            bf16x8 af = *(const bf16x8*)(sW1 + (((size_t)kc * 4 + q) * 64 + mi * 16 + l15) * 8);
            acc[mi] = __builtin_amdgcn_mfma_f32_16x16x32_bf16(af, bfr, acc[mi], 0, 0, 0);
        }
    }
    const int xx = wv * 16 + l15;
    #pragma unroll
    for (int mi = 0; mi < 4; ++mi) {              // C row cm = mi*16+q*4+r
        const int s = mi * 2 + (q >> 1);          // = (cm>>3)
        u16 pk[4];
        #pragma unroll
        for (int r = 0; r < 4; ++r)
            pk[r] = f2bf(acc[mi][r] + b1[mi * 16 + q * 4 + r]);
        *(ushort4*)(x2row + ((size_t)s * 65 + xx) * 8 + (q & 1) * 4) = *(ushort4*)&pk[0];
    }
}

// ---------------------------------------------------------------------------
// k_main: double-buffered LDS-staged phase GEMM with MASK COMPACTION.
// Grid 512 = (py, b, yP 0..31, coH). 4 waves = (rowR 2 x coQ 2).
// Staging identical to round 7. Compute: per (row,parity) the 64 columns are
// compacted into [high-list | low-list], tiles of 16, padded with sentinels
// that gather the zeroed x=64 guard granule. High steps process only the
// high tiles, low steps only low tiles -> each column pays exactly one
// branch's K (avg 160 vs 320). B-frags are per-lane LDS gathers; C is
// scatter-stored per lane.
// ---------------------------------------------------------------------------
#define SA_G 1536                                 // A granules per buffer
#define SB_G 520                                  // B granules per buffer (8*65)

template<int NR>
struct Step {
    __device__ static constexpr int count() { return NR * 10; }
    __device__ static constexpr bool hi(int c) { return c < NR * 8; }
    __device__ static constexpr int  kc(int c) { int cc = hi(c) ? c : c - NR * 8; return NR == 1 ? cc : cc >> 1; }
    __device__ static constexpr int  dy(int c) { int cc = hi(c) ? c : c - NR * 8; return NR == 1 ? 0 : (cc & 1); }
    __device__ static constexpr int  ky(int c) { return NR == 1 ? 1 : (dy(c) ? 0 : 2); }
};

template<int NR>
__device__ __forceinline__ void stage(int c, u16* sAb, u16* sBb,
                                      const u16* __restrict__ Xt,
                                      const u16* __restrict__ X2t,
                                      const u16* __restrict__ WPH,
                                      const u16* __restrict__ WPL,
                                      int b, int y0, int coH, int wid, int lane) {
    const bool hi = Step<NR>::hi(c);
    const int kc = Step<NR>::kc(c);
    const int dy = Step<NR>::dy(c);
    const int ky = Step<NR>::ky(c);
    const int kcn = hi ? 8 : 2;
    const u16* Wp = hi ? WPH : WPL;
    const u16* Xp = hi ? Xt : X2t;
    const size_t rowStr = hi ? XT_ROW : X2_ROW;
    // A: 24 segs of 64 granules; wave takes seg = i*4+wid
    #pragma unroll
    for (int i = 0; i < 6; ++i) {
        const int seg = i * 4 + wid;
        const int kx = seg >> 3, qq = (seg >> 1) & 3, h = seg & 1;
        const u16* src = Wp + ((((size_t)(ky * 3 + kx) * kcn + kc) * 4 + qq) * 256
                                + coH * 128 + h * 64 + lane) * 8;
        g2l16(src, sAb + ((size_t)((kx * 4 + qq) * 128 + h * 64)) * 8);
    }
    // B: 8 segs (2 rows x 4 q-chunks); wave wid stages q-chunk wid of each row
    #pragma unroll
    for (int i = 0; i < 2; ++i) {
        const u16* src = Xp + (size_t)(b * 65 + y0 + dy + i) * rowStr
                            + ((size_t)(kc * 4 + wid) * 65 + lane) * 8;
        g2l16(src, sBb + ((size_t)(i * 4 + wid) * 65) * 8);
    }
}

template<int NR>
__device__ __forceinline__ void run_main(const u16* __restrict__ Xt,
                                         const u16* __restrict__ X2t,
                                         const u16* __restrict__ WPH,
                                         const u16* __restrict__ WPL,
                                         const float* __restrict__ bH,
                                         const float* __restrict__ bL,
                                         const float* __restrict__ mask,
                                         float* __restrict__ out,
                                         u16* sA, u16* sB,
                                         u16* sList, u32* sCnt,
                                         int b, int y0, int py, int coH) {
    const int tid = threadIdx.x;
    const int wid = tid >> 6, lane = tid & 63, l15 = lane & 15, q = lane >> 4;
    const int rowR = wid >> 1, coQ = wid & 1;
    const int oy = 2 * (y0 + rowR) + py;
    constexpr int NS = Step<NR>::count();

    stage<NR>(0, sA, sB, Xt, X2t, WPH, WPL, b, y0, coH, wid, lane);
    __syncthreads();                              // sList init + guards visible

    // ---- build compacted lists: wave wid -> (row = wid>>1, par = wid&1) ----
    {
        const int row = wid >> 1, par = wid & 1;
        const int oyw = 2 * (y0 + row) + py;
        const float mv = mask[((size_t)b * HO + oyw) * WO + 2 * lane + par];
        const bool m = (mv != 0.f);
        unsigned long long bal = __ballot(m);
        u32 cnt = (u32)__popcll(bal);
        u32 below = __builtin_amdgcn_mbcnt_hi((u32)(bal >> 32),
                      __builtin_amdgcn_mbcnt_lo((u32)bal, 0));
        u32 teh = (cnt + 15) >> 4;
        u32 pos = m ? below : teh * 16 + ((u32)lane - below);
        sList[(row * 2 + par) * 80 + pos] = (u16)lane;
        if (lane == 0) sCnt[row * 2 + par] = cnt;
    }
    __syncthreads();                              // lists visible

    // ---- per-wave list registers (tile bounds scalar, offsets per-lane) ----
    const int baseRQ = (rowR * 4 + q) * 65;
    const u32 cntE = sCnt[rowR * 2 + 0];
    const u32 cntO = sCnt[rowR * 2 + 1];
    const int tHE = __builtin_amdgcn_readfirstlane((cntE + 15) >> 4);
    const int tTE = __builtin_amdgcn_readfirstlane(((cntE + 15) >> 4) + ((64 - cntE + 15) >> 4));
    const int tHO = __builtin_amdgcn_readfirstlane((cntO + 15) >> 4);
    const int tTO = __builtin_amdgcn_readfirstlane(((cntO + 15) >> 4) + ((64 - cntO + 15) >> 4));
    int offE[5], offO2[5], offO0[5];
    #pragma unroll
    for (int t = 0; t < 5; ++t) {
        const u16 eE = sList[(rowR * 2 + 0) * 80 + t * 16 + l15];
        const u16 eO = sList[(rowR * 2 + 1) * 80 + t * 16 + l15];
        const int ixE = (eE == 0xFFFF) ? 64 : (int)eE;
        const int ix2 = (eO == 0xFFFF) ? 64 : (int)eO;
        const int ix0 = (eO == 0xFFFF) ? 64 : (int)eO + 1;
        offE[t]  = (baseRQ + ixE) * 8;
        offO2[t] = (baseRQ + ix2) * 8;
        offO0[t] = (baseRQ + ix0) * 8;
    }

    f32x4 accE[5][4] = {}, accO[5][4] = {};

    #pragma unroll
    for (int c = 0; c < NS; ++c) {
        if (c + 1 < NS)
            stage<NR>(c + 1, sA + ((c + 1) & 1) * (SA_G * 8), sB + ((c + 1) & 1) * (SB_G * 8),
                      Xt, X2t, WPH, WPL, b, y0, coH, wid, lane);
        // ---- compute step c ----
        {
            const u16* sAb = sA + (c & 1) * (SA_G * 8);
            const u16* sBb = sB + (c & 1) * (SB_G * 8);
            const u16* ap = sAb + ((size_t)(q * 128 + coQ * 64 + l15)) * 8;
            // even phase: tap kx=1
            {
                bf16x8 aE[4];
                #pragma unroll
                for (int mi = 0; mi < 4; ++mi)
                    aE[mi] = *(const bf16x8*)(ap + (512 + mi * 16) * 8);
                const int t0 = Step<NR>::hi(c) ? 0 : tHE;
                const int t1 = Step<NR>::hi(c) ? tHE : tTE;
                #pragma unroll
                for (int t = 0; t < 5; ++t) {
                    if (t >= t0 && t < t1) {
                        bf16x8 bf = *(const bf16x8*)(sBb + offE[t]);
                        #pragma unroll
                        for (int mi = 0; mi < 4; ++mi)
                            accE[t][mi] = __builtin_amdgcn_mfma_f32_16x16x32_bf16(
                                aE[mi], bf, accE[t][mi], 0, 0, 0);
                    }
                }
            }
            // odd phase: taps kx=2 (ix) and kx=0 (ix+1)
            {
                bf16x8 a2[4], a0[4];
                #pragma unroll
                for (int mi = 0; mi < 4; ++mi) {
                    a2[mi] = *(const bf16x8*)(ap + (1024 + mi * 16) * 8);
                    a0[mi] = *(const bf16x8*)(ap + (mi * 16) * 8);
                }
                const int t0 = Step<NR>::hi(c) ? 0 : tHO;
                const int t1 = Step<NR>::hi(c) ? tHO : tTO;
                #pragma unroll
                for (int t = 0; t < 5; ++t) {
                    if (t >= t0 && t < t1) {
                        bf16x8 b2 = *(const bf16x8*)(sBb + offO2[t]);
                        bf16x8 b0 = *(const bf16x8*)(sBb + offO0[t]);
                        #pragma unroll
                        for (int mi = 0; mi < 4; ++mi)
                            accO[t][mi] = __builtin_amdgcn_mfma_f32_16x16x32_bf16(
                                a2[mi], b2, accO[t][mi], 0, 0, 0);
                        #pragma unroll
                        for (int mi = 0; mi < 4; ++mi)
                            accO[t][mi] = __builtin_amdgcn_mfma_f32_16x16x32_bf16(
                                a0[mi], b0, accO[t][mi], 0, 0, 0);
                    }
                }
            }
        }
        __syncthreads();
    }

    // ---- epilogue: per-slot branch bias, per-lane scatter stores ----
    #pragma unroll
    for (int mi = 0; mi < 4; ++mi) {
        const int cob = coH * 128 + coQ * 64 + mi * 16 + q * 4;
        float bh[4], bl[4];
        #pragma unroll
        for (int r = 0; r < 4; ++r) { bh[r] = bH[cob + r]; bl[r] = bL[cob + r]; }
        #pragma unroll
        for (int t = 0; t < 5; ++t) {
            if (t < tTE) {
                const bool isH = t < tHE;
                const int ixE = offE[t] / 8 - baseRQ;
                if (ixE < 64) {
                    const int ox = 2 * ixE;
                    #pragma unroll
                    for (int r = 0; r < 4; ++r)
                        out[(((size_t)(b * COUT + cob + r)) * HO + oy) * WO + ox] =
                            accE[t][mi][r] + (isH ? bh[r] : bl[r]);
                }
            }
            if (t < tTO) {
                const bool isH = t < tHO;
                const int ix2 = offO2[t] / 8 - baseRQ;
                if (ix2 < 64) {
                    const int ox = 2 * ix2 + 1;
                    #pragma unroll
                    for (int r = 0; r < 4; ++r)
                        out[(((size_t)(b * COUT + cob + r)) * HO + oy) * WO + ox] =
                            accO[t][mi][r] + (isH ? bh[r] : bl[r]);
                }
            }
        }
    }
}

__global__ __launch_bounds__(256, 2) void k_main(const u16* __restrict__ Xt,
                                                 const u16* __restrict__ X2t,
                                                 const u16* __restrict__ WPH,
                                                 const u16* __restrict__ WPL,
                                                 const float* __restrict__ bH,
                                                 const float* __restrict__ bL,
                                                 const float* __restrict__ mask,
                                                 float* __restrict__ out) {
    __shared__ u16 sA[2][SA_G * 8];               // 2 x 24576 B
    __shared__ u16 sB[2][SB_G * 8];               // 2 x  8320 B
    __shared__ u16 sList[4 * 80];                 // compacted column lists
    __shared__ u32 sCnt[4];

    const int blk = blockIdx.x;
    const int coH = blk & 1;
    const int yP  = (blk >> 1) & 31;
    const int b   = (blk >> 6) & 3;
    const int py  = blk >> 8;
    const int y0  = yP * 2;
    const int tid = threadIdx.x;

    if (tid < 16) {                               // zero B x-guard granules
        uint4 z = {0, 0, 0, 0};
        *(uint4*)(sB[tid >> 3] + (((size_t)(tid & 7)) * 65 + 64) * 8) = z;
    }
    if (tid < 160) ((u32*)sList)[tid] = 0xFFFFFFFFu;   // sentinel-init lists

    if (py == 0)
        run_main<1>(Xt, X2t, WPH, WPL, bH, bL, mask, out,
                    &sA[0][0], &sB[0][0], sList, sCnt, b, y0, py, coH);
    else
        run_main<2>(Xt, X2t, WPH, WPL, bH, bL, mask, out,
                    &sA[0][0], &sB[0][0], sList, sCnt, b, y0, py, coH);
}

// ---------------------------------------------------------------------------
extern "C" void kernel_launch(void* const* d_in, const int* in_sizes, int n_in,
                              void* d_out, int out_size, void* d_ws, size_t ws_size,
                              hipStream_t stream) {
    const float* inx    = (const float*)d_in[0];
    const float* mask   = (const float*)d_in[1];
    // d_in[2] = inv_mask (unused: mask is exactly 0/1)
    const float* w_high = (const float*)d_in[3];
    const float* b_high = (const float*)d_in[4];
    const float* w_low1 = (const float*)d_in[5];
    const float* b_low1 = (const float*)d_in[6];
    const float* w_low2 = (const float*)d_in[7];
    const float* b_low2 = (const float*)d_in[8];
    float* out = (float*)d_out;

    char* ws = (char*)d_ws;
    u16* Xt  = (u16*)(ws);                 //  8,652,800 B
    u16* X2t = (u16*)(ws + 8652800);       //  2,163,200 B
    u16* WPH = (u16*)(ws + 10816000);      //  1,179,648 B
    u16* WPL = (u16*)(ws + 11995648);      //    294,912 B  (total ~12.3 MiB)

    k_prep<<<BATCH * 65 + 72, 256, 0, stream>>>(inx, w_low1, b_low1, w_high, w_low2,
                                                Xt, X2t, WPH, WPL);
    k_main<<<512, 256, 0, stream>>>(Xt, X2t, WPH, WPL, b_high, b_low2, mask, out);
}